// Round 2
// baseline (3090.428 us; speedup 1.0000x reference)
//
#include <hip/hip_runtime.h>
#include <hip/hip_bf16.h>
#include <cstdint>
#include <cstddef>

typedef __hip_bfloat16 bf16;

constexpr int Bn = 4, Sn = 2048, Dn = 1024, Hn = 16, HDn = 64;
constexpr size_t BSD = (size_t)Bn * Sn * Dn;   // 8,388,608

__device__ __forceinline__ float b2f_raw(unsigned short u) {
    union { unsigned int i; float f; } x; x.i = ((unsigned int)u) << 16; return x.f;
}

// load 4 consecutive elements as float4 (overloaded on storage type)
__device__ __forceinline__ float4 ld4f(const float* p) { return *(const float4*)p; }
__device__ __forceinline__ float4 ld4f(const bf16* p) {
    ushort4 u = *(const ushort4*)p;
    return make_float4(b2f_raw(u.x), b2f_raw(u.y), b2f_raw(u.z), b2f_raw(u.w));
}
__device__ __forceinline__ void st1(float* p, float v) { *p = v; }
__device__ __forceinline__ void st1(bf16* p, float v)  { *p = __float2bfloat16(v); }

// ---------------------------------------------------------------------------
// Input-dtype detection: interpret the first 4096 uint16 of Wq as bf16.
// True bf16 N(0,1/32) data -> all exponents <= ~0x7C (zero hits).
// fp32 data read as uint16 halves -> low halves have uniform exponent bits,
// ~25% >= 0xC0 (~1000 hits). flag: 0 = fp32 inputs, 1 = bf16 inputs.
// ---------------------------------------------------------------------------
__global__ void detect_dtype(const unsigned short* __restrict__ w, int* __restrict__ flag) {
    __shared__ int cnt;
    if (threadIdx.x == 0) cnt = 0;
    __syncthreads();
    int local = 0;
    for (int i = threadIdx.x; i < 4096; i += 256) {
        const int e = (w[i] >> 7) & 0xFF;
        if (e >= 0xC0) local++;
    }
    atomicAdd(&cnt, local);
    __syncthreads();
    if (threadIdx.x == 0) *flag = (cnt > 16) ? 0 : 1;
}

// ---------------------------------------------------------------------------
// GEMM: C = A[M,K] @ W[K,N], M=8192, N=K=1024. 64x64 tile, BK=16, 256 thr,
// 4x4 outputs/thread, fp32 accumulate. headsplit=1 writes C in [B,H,S,HD].
// blockIdx.z selects one of three (A,W,C) triples (QKV fused launch).
// WANT-guarded: whole block returns unless *dflag == WANT.
// ---------------------------------------------------------------------------
template<typename TIN, typename TOUT, int WANT>
__global__ __launch_bounds__(256) void gemm64(
    const TIN* __restrict__ A0, const TIN* __restrict__ A1, const TIN* __restrict__ A2,
    const TIN* __restrict__ W0, const TIN* __restrict__ W1, const TIN* __restrict__ W2,
    TOUT* __restrict__ C0, TOUT* __restrict__ C1, TOUT* __restrict__ C2,
    int headsplit, const int* __restrict__ dflag)
{
    if (*dflag != WANT) return;   // uniform, before any barrier

    constexpr int N = Dn, K = Dn;
    constexpr int BM = 64, BN = 64, BK = 16;
    const int z = blockIdx.z;
    const TIN* A = (z == 0) ? A0 : ((z == 1) ? A1 : A2);
    const TIN* W = (z == 0) ? W0 : ((z == 1) ? W1 : W2);
    TOUT*      C = (z == 0) ? C0 : ((z == 1) ? C1 : C2);

    // A stored transposed in LDS: As[k][m]; +4 pad keeps float4 alignment
    // (stride 68 floats = 272 B, 16B-divisible) and spreads banks.
    __shared__ float As[BK][BM + 4];
    __shared__ float Bs[BK][BN + 4];

    const int t  = threadIdx.x;
    const int tx = t & 15, ty = t >> 4;
    const int row0 = blockIdx.y * BM;
    const int col0 = blockIdx.x * BN;

    const int a_r = t >> 2, a_c = (t & 3) * 4;    // 64 rows x 16 cols, 4 elems/thr
    const int b_r = t >> 4, b_c = (t & 15) * 4;   // 16 rows x 64 cols, 4 elems/thr

    float acc[4][4] = {};

    for (int k0 = 0; k0 < K; k0 += BK) {
        float4 av = ld4f(A + (size_t)(row0 + a_r) * K + (k0 + a_c));
        float4 bv = ld4f(W + (size_t)(k0 + b_r) * N + (col0 + b_c));
        As[a_c + 0][a_r] = av.x; As[a_c + 1][a_r] = av.y;
        As[a_c + 2][a_r] = av.z; As[a_c + 3][a_r] = av.w;
        Bs[b_r][b_c + 0] = bv.x; Bs[b_r][b_c + 1] = bv.y;
        Bs[b_r][b_c + 2] = bv.z; Bs[b_r][b_c + 3] = bv.w;
        __syncthreads();
        #pragma unroll
        for (int kk = 0; kk < BK; ++kk) {
            float4 a4 = *(const float4*)&As[kk][ty * 4];
            float4 b4 = *(const float4*)&Bs[kk][tx * 4];
            float ar[4] = {a4.x, a4.y, a4.z, a4.w};
            float br[4] = {b4.x, b4.y, b4.z, b4.w};
            #pragma unroll
            for (int i = 0; i < 4; i++)
                #pragma unroll
                for (int j = 0; j < 4; j++)
                    acc[i][j] = fmaf(ar[i], br[j], acc[i][j]);
        }
        __syncthreads();
    }

    #pragma unroll
    for (int i = 0; i < 4; i++) {
        const int m = row0 + ty * 4 + i;
        #pragma unroll
        for (int j = 0; j < 4; j++) {
            const int n = col0 + tx * 4 + j;
            size_t idx;
            if (headsplit) {
                const int b = m >> 11, s = m & (Sn - 1);     // S = 2048
                const int h = n >> 6,  hd = n & (HDn - 1);   // HD = 64
                idx = (((size_t)(b * Hn + h)) * Sn + s) * HDn + hd;
            } else {
                idx = (size_t)m * N + n;
            }
            st1(C + idx, acc[i][j]);
        }
    }
}

// ---------------------------------------------------------------------------
// Flash-style attention: block = (b, h, 32-query tile), 256 threads.
// K/V tiles of 64 in LDS, online softmax, output accumulated in registers.
// Key tiles fully past valid_len[b] are skipped (masked entries are -1e6 ->
// exp == 0 in fp32 -> exact vs reference).
// ---------------------------------------------------------------------------
template<typename TS>
__global__ __launch_bounds__(256) void attn32(
    const TS* __restrict__ Qh, const TS* __restrict__ Kh, const TS* __restrict__ Vh,
    const int* __restrict__ vlen, TS* __restrict__ Out)
{
    constexpr int TQ = 32, TK = 64;
    __shared__ float Qs[TQ][HDn + 4];
    __shared__ float Ks[TK][HDn + 4];
    __shared__ float Vs[TK][HDn + 4];
    __shared__ float Scs[TQ][TK + 4];
    __shared__ float mrow[TQ], lrow[TQ], arow[TQ];

    const int t = threadIdx.x;
    constexpr int NTQ = Sn / TQ;                 // 64
    const int qt = blockIdx.x % NTQ;
    const int h  = (blockIdx.x / NTQ) % Hn;
    const int b  = blockIdx.x / (NTQ * Hn);
    const int q0 = qt * TQ;
    const int vl = vlen[b];

    const size_t hoff = ((size_t)(b * Hn + h)) * Sn * HDn;
    const TS* Qg = Qh + hoff + (size_t)q0 * HDn;
    const TS* Kg = Kh + hoff;
    const TS* Vg = Vh + hoff;

    {   // load Q tile (scaled by 1/sqrt(HD) = 0.125): 8 elems/thread
        const int idx = t * 8, qq = idx >> 6, dd = idx & 63;
        float4 v0 = ld4f(Qg + idx), v1 = ld4f(Qg + idx + 4);
        Qs[qq][dd + 0] = v0.x * 0.125f; Qs[qq][dd + 1] = v0.y * 0.125f;
        Qs[qq][dd + 2] = v0.z * 0.125f; Qs[qq][dd + 3] = v0.w * 0.125f;
        Qs[qq][dd + 4] = v1.x * 0.125f; Qs[qq][dd + 5] = v1.y * 0.125f;
        Qs[qq][dd + 6] = v1.z * 0.125f; Qs[qq][dd + 7] = v1.w * 0.125f;
    }
    if (t < TQ) { mrow[t] = -INFINITY; lrow[t] = 0.0f; }

    float acc[8] = {};
    const int pd  = t & 63;          // PV: my head-dim column
    const int pq0 = t >> 6;          // PV: q = pq0 + 4*i
    const int sq  = t & 31;          // scores: my query row
    const int sk0 = (t >> 5) << 3;   // scores: my 8 keys

    const int ntiles = (vl + TK - 1) / TK;   // vl in [1, S]

    for (int kt = 0; kt < ntiles; ++kt) {
        const int ks0 = kt * TK;
        __syncthreads();   // protect K/V/Sc from prior iteration's readers
        {   // load K,V tile: 16 elems/thread, coalesced 32B runs
            const int kk = t >> 2, dd = (t & 3) << 4;
            const TS* kp = Kg + (size_t)(ks0 + kk) * HDn + dd;
            const TS* vp = Vg + (size_t)(ks0 + kk) * HDn + dd;
            #pragma unroll
            for (int u = 0; u < 4; u++) {
                float4 kv = ld4f(kp + u * 4);
                Ks[kk][dd + u*4 + 0] = kv.x; Ks[kk][dd + u*4 + 1] = kv.y;
                Ks[kk][dd + u*4 + 2] = kv.z; Ks[kk][dd + u*4 + 3] = kv.w;
                float4 vv = ld4f(vp + u * 4);
                Vs[kk][dd + u*4 + 0] = vv.x; Vs[kk][dd + u*4 + 1] = vv.y;
                Vs[kk][dd + u*4 + 2] = vv.z; Vs[kk][dd + u*4 + 3] = vv.w;
            }
        }
        __syncthreads();
        // scores: 8 per thread
        #pragma unroll
        for (int j = 0; j < 8; j++) {
            const int k = sk0 + j;
            const float* qp = &Qs[sq][0];
            const float* kp = &Ks[k][0];
            float s = 0.0f;
            #pragma unroll
            for (int dd = 0; dd < HDn; dd += 4) {
                float4 qa = *(const float4*)(qp + dd);
                float4 kb = *(const float4*)(kp + dd);
                s = fmaf(qa.x, kb.x, fmaf(qa.y, kb.y, fmaf(qa.z, kb.z, fmaf(qa.w, kb.w, s))));
            }
            Scs[sq][k] = (ks0 + k < vl) ? s : -1e6f;
        }
        __syncthreads();
        // online-softmax row update (one thread per query row)
        if (t < TQ) {
            float m = mrow[t], tm = -INFINITY;
            for (int k = 0; k < TK; k++) tm = fmaxf(tm, Scs[t][k]);
            const float mnew = fmaxf(m, tm);
            const float al = __expf(m - mnew);          // exp(-inf)=0 on tile 0
            float sum = 0.0f;
            for (int k = 0; k < TK; k++) {
                const float p = __expf(Scs[t][k] - mnew);
                Scs[t][k] = p; sum += p;
            }
            lrow[t] = lrow[t] * al + sum;
            mrow[t] = mnew;
            arow[t] = al;
        }
        __syncthreads();
        // PV accumulate: 8 (q,d) pairs/thread
        #pragma unroll
        for (int i = 0; i < 8; i++) acc[i] *= arow[pq0 + 4 * i];
        for (int k = 0; k < TK; k++) {
            const float v = Vs[k][pd];
            #pragma unroll
            for (int i = 0; i < 8; i++)
                acc[i] = fmaf(Scs[pq0 + 4 * i][k], v, acc[i]);
        }
    }

    #pragma unroll
    for (int i = 0; i < 8; i++) {
        const int q = pq0 + 4 * i;
        const float o = acc[i] / lrow[q];
        st1(Out + ((size_t)b * Sn + q0 + q) * Dn + (size_t)h * HDn + pd, o);
    }
}

// ---------------------------------------------------------------------------
// Pipeline: scratch dtype TS chosen on host from ws_size; input/output dtype
// chosen at runtime by the device flag (both variants launched, one no-ops).
// ---------------------------------------------------------------------------
template<typename TS>
static void run_pipeline(void* const* d_in, void* d_out, void* d_ws, hipStream_t stream)
{
    const float* qf  = (const float*)d_in[0];
    const float* kf  = (const float*)d_in[1];
    const float* vf  = (const float*)d_in[2];
    const int*   vl  = (const int*)d_in[3];
    const float* Wqf = (const float*)d_in[4];
    const float* Wkf = (const float*)d_in[5];
    const float* Wvf = (const float*)d_in[6];
    const float* Wof = (const float*)d_in[7];
    const bf16* qb  = (const bf16*)d_in[0];
    const bf16* kb  = (const bf16*)d_in[1];
    const bf16* vb  = (const bf16*)d_in[2];
    const bf16* Wqb = (const bf16*)d_in[4];
    const bf16* Wkb = (const bf16*)d_in[5];
    const bf16* Wvb = (const bf16*)d_in[6];
    const bf16* Wob = (const bf16*)d_in[7];

    int* flag = (int*)d_ws;
    TS*  Qh   = (TS*)((char*)d_ws + 256);
    TS*  Kh   = Qh + BSD;
    TS*  Vh   = Kh + BSD;
    TS*  Ao   = Vh + BSD;

    detect_dtype<<<1, 256, 0, stream>>>((const unsigned short*)d_in[4], flag);

    dim3 g3(Dn / 64, (Bn * Sn) / 64, 3);
    dim3 g1(Dn / 64, (Bn * Sn) / 64, 1);

    // QKV projections, head-split layout [B,H,S,HD]
    gemm64<float, TS, 0><<<g3, 256, 0, stream>>>(qf, kf, vf, Wqf, Wkf, Wvf, Qh, Kh, Vh, 1, flag);
    gemm64<bf16,  TS, 1><<<g3, 256, 0, stream>>>(qb, kb, vb, Wqb, Wkb, Wvb, Qh, Kh, Vh, 1, flag);
    // attention -> [B,S,D] (heads merged); dtype-independent
    attn32<TS><<<dim3(Bn * Hn * (Sn / 32)), 256, 0, stream>>>(Qh, Kh, Vh, vl, Ao);
    // output projection; out dtype follows detected input dtype
    gemm64<TS, float, 0><<<g1, 256, 0, stream>>>(Ao, Ao, Ao, (const TS*)Qh, (const TS*)Qh, (const TS*)Qh,
                                                 (float*)d_out, (float*)d_out, (float*)d_out, 0, flag);
    gemm64<TS, bf16,  1><<<g1, 256, 0, stream>>>(Ao, Ao, Ao, (const TS*)Qh, (const TS*)Qh, (const TS*)Qh,
                                                 (bf16*)d_out, (bf16*)d_out, (bf16*)d_out, 0, flag);
}

// The final-projection weight must be W (not Qh). Fix with a thin wrapper that
// passes the real weight in both dtype views.
template<typename TS>
static void run_pipeline_fixed(void* const* d_in, void* d_out, void* d_ws, hipStream_t stream)
{
    const int* vl = (const int*)d_in[3];

    int* flag = (int*)d_ws;
    TS*  Qh   = (TS*)((char*)d_ws + 256);
    TS*  Kh   = Qh + BSD;
    TS*  Vh   = Kh + BSD;
    TS*  Ao   = Vh + BSD;

    detect_dtype<<<1, 256, 0, stream>>>((const unsigned short*)d_in[4], flag);

    dim3 g3(Dn / 64, (Bn * Sn) / 64, 3);
    dim3 g1(Dn / 64, (Bn * Sn) / 64, 1);

    gemm64<float, TS, 0><<<g3, 256, 0, stream>>>(
        (const float*)d_in[0], (const float*)d_in[1], (const float*)d_in[2],
        (const float*)d_in[4], (const float*)d_in[5], (const float*)d_in[6],
        Qh, Kh, Vh, 1, flag);
    gemm64<bf16, TS, 1><<<g3, 256, 0, stream>>>(
        (const bf16*)d_in[0], (const bf16*)d_in[1], (const bf16*)d_in[2],
        (const bf16*)d_in[4], (const bf16*)d_in[5], (const bf16*)d_in[6],
        Qh, Kh, Vh, 1, flag);

    attn32<TS><<<dim3(Bn * Hn * (Sn / 32)), 256, 0, stream>>>(Qh, Kh, Vh, vl, Ao);

    // Wo must be read in TS for the template; stage it: for simplicity the
    // fp32-flag variant reads Wo as float via a TIN=TS trick is not possible,
    // so we instead give gemm64 a separate weight type equal to TIN of the
    // *input* dtype by converting Ao: instead, instantiate with TIN matching
    // Ao and pass Wo через a dtype-matched copy is unnecessary — gemm64's W
    // type equals TIN, and Ao is TS. So we need Wo in TS. Convert once below.
    (void)g1;
}

// ---------------------------------------------------------------------------
// Wo dtype bridge: gemm64's W operand shares TIN with A. For the final
// projection A=Ao (dtype TS) while Wo is the raw input (fp32 or bf16). A tiny
// conversion kernel rewrites Wo into TS scratch, guarded by the flag.
// ---------------------------------------------------------------------------
template<typename TW, typename TS, int WANT>
__global__ __launch_bounds__(256) void conv_w(
    const TW* __restrict__ src, TS* __restrict__ dst, const int* __restrict__ dflag)
{
    if (*dflag != WANT) return;
    const size_t i = (size_t)blockIdx.x * 1024 + threadIdx.x * 4;
    float4 v = ld4f(src + i);
    st1(dst + i + 0, v.x); st1(dst + i + 1, v.y);
    st1(dst + i + 2, v.z); st1(dst + i + 3, v.w);
}

template<typename TS>
static void run_all(void* const* d_in, void* d_out, void* d_ws, hipStream_t stream)
{
    const int* vl = (const int*)d_in[3];

    int* flag = (int*)d_ws;
    TS*  Qh   = (TS*)((char*)d_ws + 256);
    TS*  Kh   = Qh + BSD;
    TS*  Vh   = Kh + BSD;
    TS*  Ao   = Vh + BSD;
    TS*  WoS  = Ao + BSD;   // Dn*Dn elements of TS for converted Wo

    detect_dtype<<<1, 256, 0, stream>>>((const unsigned short*)d_in[4], flag);

    dim3 g3(Dn / 64, (Bn * Sn) / 64, 3);
    dim3 g1(Dn / 64, (Bn * Sn) / 64, 1);

    gemm64<float, TS, 0><<<g3, 256, 0, stream>>>(
        (const float*)d_in[0], (const float*)d_in[1], (const float*)d_in[2],
        (const float*)d_in[4], (const float*)d_in[5], (const float*)d_in[6],
        Qh, Kh, Vh, 1, flag);
    gemm64<bf16, TS, 1><<<g3, 256, 0, stream>>>(
        (const bf16*)d_in[0], (const bf16*)d_in[1], (const bf16*)d_in[2],
        (const bf16*)d_in[4], (const bf16*)d_in[5], (const bf16*)d_in[6],
        Qh, Kh, Vh, 1, flag);

    attn32<TS><<<dim3(Bn * Hn * (Sn / 32)), 256, 0, stream>>>(Qh, Kh, Vh, vl, Ao);

    conv_w<float, TS, 0><<<dim3(Dn * Dn / 1024), 256, 0, stream>>>((const float*)d_in[7], WoS, flag);
    conv_w<bf16,  TS, 1><<<dim3(Dn * Dn / 1024), 256, 0, stream>>>((const bf16*)d_in[7],  WoS, flag);

    gemm64<TS, float, 0><<<g1, 256, 0, stream>>>(Ao, Ao, Ao, WoS, WoS, WoS,
        (float*)d_out, (float*)d_out, (float*)d_out, 0, flag);
    gemm64<TS, bf16,  1><<<g1, 256, 0, stream>>>(Ao, Ao, Ao, WoS, WoS, WoS,
        (bf16*)d_out, (bf16*)d_out, (bf16*)d_out, 0, flag);
}

extern "C" void kernel_launch(void* const* d_in, const int* in_sizes, int n_in,
                              void* d_out, int out_size, void* d_ws, size_t ws_size,
                              hipStream_t stream)
{
    // scratch: 4*BSD (Q,K,V,Ao) + Dn*Dn (converted Wo) elements + 256 B flag
    const size_t need_f32 = 256 + (4 * BSD + (size_t)Dn * Dn) * sizeof(float);
    if (ws_size >= need_f32) {
        run_all<float>(d_in, d_out, d_ws, stream);
    } else {
        run_all<bf16>(d_in, d_out, d_ws, stream);
    }
}